// Round 2
// baseline (1074.796 us; speedup 1.0000x reference)
//
#include <hip/hip_runtime.h>
#include <hip/hip_bf16.h>

// Problem constants (from setup_inputs): N=200000, C=128, K=32, B=16, 20 iters.
#define C_DIM 128
#define K_DIM 32
#define N_ITERS 20

// ---------------------------------------------------------------------------
// init: zero d_out accumulator and v/colsum state in ws
// ---------------------------------------------------------------------------
__global__ void init_kernel(float* __restrict__ out, float* __restrict__ vcs,
                            int n_out, int n_vcs) {
    int i = blockIdx.x * blockDim.x + threadIdx.x;
    int stride = gridDim.x * blockDim.x;
    for (int j = i; j < n_out; j += stride) out[j] = 0.f;
    for (int j = i; j < n_vcs; j += stride) vcs[j] = 0.f;
}

// ---------------------------------------------------------------------------
// fused MLP: logits = (relu(x@W1 + b1) @ W2 + b2) * scaling   -> L [N,32]
// 512 threads (8 waves), 64-row tiles. W1 staged in 16KB QUARTERS (32 k-rows)
// so total LDS ~65KB -> 2 blocks/CU (occupancy fix vs 113KB/1-block).
// wave w owns rows 8w..8w+7 of the tile; lane l owns cols {2l,2l+1} (layer 1).
// ---------------------------------------------------------------------------
__global__ __launch_bounds__(512) void mlp_kernel(
    const float* __restrict__ x, const float* __restrict__ W1,
    const float* __restrict__ b1, const float* __restrict__ W2,
    const float* __restrict__ b2, const float* __restrict__ scal,
    float* __restrict__ Lg, int N, int ntiles) {
    __shared__ float sW1q[32 * C_DIM];     // 16 KB, quarter of W1: [k][c]
    __shared__ float sW2[C_DIM * K_DIM];   // 16 KB, [c][kk]
    __shared__ float sB1[C_DIM];
    __shared__ float sB2[K_DIM];
    __shared__ float sT[64][C_DIM];        // 32 KB, x tile then h tile

    const int tid = threadIdx.x;
    for (int i = tid; i < C_DIM * K_DIM / 4; i += 512)
        ((float4*)sW2)[i] = ((const float4*)W2)[i];
    if (tid < C_DIM / 4) ((float4*)sB1)[tid] = ((const float4*)b1)[tid];
    if (tid < K_DIM / 4) ((float4*)sB2)[tid] = ((const float4*)b2)[tid];
    const float sc = *scal;

    const int wave = tid >> 6;
    const int lane = tid & 63;
    const int r0 = wave * 8;

    for (int tile = blockIdx.x; tile < ntiles; tile += gridDim.x) {
        const int row0 = tile * 64;   // N = 200000 = 64*3125, always full tiles
        __syncthreads();  // previous tile fully consumed before overwrite
        // ---- stage x tile (rows are contiguous; linear float4 copy) ----
        {
            const float4* src = (const float4*)(x + (size_t)row0 * C_DIM);
            ((float4*)&sT[0][0])[tid]        = src[tid];
            ((float4*)&sT[0][0])[tid + 512]  = src[tid + 512];
            ((float4*)&sT[0][0])[tid + 1024] = src[tid + 1024];
            ((float4*)&sT[0][0])[tid + 1536] = src[tid + 1536];
        }
        __syncthreads();

        // ---- layer 1: h = relu(x@W1 + b1), 8 rows x 2 cols per lane ----
        float acc[8][2];
#pragma unroll
        for (int r = 0; r < 8; ++r) {
            acc[r][0] = sB1[2 * lane];
            acc[r][1] = sB1[2 * lane + 1];
        }
        for (int q = 0; q < 4; ++q) {
            // stage W1 rows q*32 .. q*32+31 (1024 float4, 2 per thread)
            {
                const float4* wsrc = (const float4*)(W1 + (size_t)q * 32 * C_DIM);
                ((float4*)sW1q)[tid]       = wsrc[tid];
                ((float4*)sW1q)[tid + 512] = wsrc[tid + 512];
            }
            __syncthreads();
#pragma unroll 2
            for (int kc = 0; kc < 8; ++kc) {
                const int k = kc * 4;               // local k within quarter
                const int kg = q * 32 + k;          // global k (x index)
                const float2 w0 = *(const float2*)&sW1q[(k + 0) * C_DIM + 2 * lane];
                const float2 w1 = *(const float2*)&sW1q[(k + 1) * C_DIM + 2 * lane];
                const float2 w2 = *(const float2*)&sW1q[(k + 2) * C_DIM + 2 * lane];
                const float2 w3 = *(const float2*)&sW1q[(k + 3) * C_DIM + 2 * lane];
#pragma unroll
                for (int r = 0; r < 8; ++r) {
                    const float4 xv = *(const float4*)&sT[r0 + r][kg];  // broadcast
                    acc[r][0] = fmaf(xv.x, w0.x, acc[r][0]);
                    acc[r][1] = fmaf(xv.x, w0.y, acc[r][1]);
                    acc[r][0] = fmaf(xv.y, w1.x, acc[r][0]);
                    acc[r][1] = fmaf(xv.y, w1.y, acc[r][1]);
                    acc[r][0] = fmaf(xv.z, w2.x, acc[r][0]);
                    acc[r][1] = fmaf(xv.z, w2.y, acc[r][1]);
                    acc[r][0] = fmaf(xv.w, w3.x, acc[r][0]);
                    acc[r][1] = fmaf(xv.w, w3.y, acc[r][1]);
                }
            }
            __syncthreads();  // quarter consumed before restage
        }
        // write h back into own rows (same-wave WAR on LDS is in-order safe)
#pragma unroll
        for (int r = 0; r < 8; ++r) {
            float2 hv;
            hv.x = fmaxf(acc[r][0], 0.f);
            hv.y = fmaxf(acc[r][1], 0.f);
            *(float2*)&sT[r0 + r][2 * lane] = hv;
        }

        // ---- layer 2: logits = (h@W2 + b2)*sc ; 1 row x 4 kk per lane ----
        // (reads only this wave's rows of sT -> no block sync needed)
        const int r2 = lane & 7;
        const int kk0 = (lane >> 3) * 4;
        float a2[4];
        a2[0] = sB2[kk0];
        a2[1] = sB2[kk0 + 1];
        a2[2] = sB2[kk0 + 2];
        a2[3] = sB2[kk0 + 3];
#pragma unroll 4
        for (int c = 0; c < C_DIM; c += 4) {
            const float4 hv = *(const float4*)&sT[r0 + r2][c];
            const float4 q0 = *(const float4*)&sW2[(c + 0) * K_DIM + kk0];
            const float4 q1 = *(const float4*)&sW2[(c + 1) * K_DIM + kk0];
            const float4 q2 = *(const float4*)&sW2[(c + 2) * K_DIM + kk0];
            const float4 q3 = *(const float4*)&sW2[(c + 3) * K_DIM + kk0];
            a2[0] = fmaf(hv.x, q0.x, a2[0]); a2[1] = fmaf(hv.x, q0.y, a2[1]);
            a2[2] = fmaf(hv.x, q0.z, a2[2]); a2[3] = fmaf(hv.x, q0.w, a2[3]);
            a2[0] = fmaf(hv.y, q1.x, a2[0]); a2[1] = fmaf(hv.y, q1.y, a2[1]);
            a2[2] = fmaf(hv.y, q1.z, a2[2]); a2[3] = fmaf(hv.y, q1.w, a2[3]);
            a2[0] = fmaf(hv.z, q2.x, a2[0]); a2[1] = fmaf(hv.z, q2.y, a2[1]);
            a2[2] = fmaf(hv.z, q2.z, a2[2]); a2[3] = fmaf(hv.z, q2.w, a2[3]);
            a2[0] = fmaf(hv.w, q3.x, a2[0]); a2[1] = fmaf(hv.w, q3.y, a2[1]);
            a2[2] = fmaf(hv.w, q3.z, a2[2]); a2[3] = fmaf(hv.w, q3.w, a2[3]);
        }
        const int g = row0 + r0 + r2;
        if (g < N) {
            float4 o = make_float4(a2[0] * sc, a2[1] * sc, a2[2] * sc, a2[3] * sc);
            *(float4*)&Lg[(size_t)g * K_DIM + kk0] = o;
        }
    }
}

// ---------------------------------------------------------------------------
// one Sinkhorn iteration t (1-based):
//   v_{t-1} = v_{t-2} + log(colsum_{t-1}) - log(N/K)    (recomputed per block)
//   per row: u = LSE_k(L - v_{t-1}); accumulate colsum_t[k] += exp(L-v-u)
// Column reduce: 5-stage fold-exchange (16+8+4+2+1 shfl) + final xor32
//  -> 32 shuffles/thread instead of 192. Lane l ends holding the 64-lane sum
//     of column bitrev5(l&31).
// ---------------------------------------------------------------------------
__device__ __forceinline__ int bitrev5(int l) {
    return ((l & 1) << 4) | ((l & 2) << 2) | (l & 4) | ((l & 8) >> 2) |
           ((l & 16) >> 4);
}

__global__ __launch_bounds__(512) void sinkhorn_iter_kernel(
    const float* __restrict__ Lg, float* __restrict__ vbuf,
    float* __restrict__ colsum, int t, int N) {
    __shared__ float sv[K_DIM];
    __shared__ float swsum[8][K_DIM];   // per-wave column sums
    const int tid = threadIdx.x;
    const int wave = tid >> 6;
    const int lane = tid & 63;

    if (tid < K_DIM) {
        float vp = 0.f;
        if (t > 1)
            vp = vbuf[(t - 2) * K_DIM + tid] +
                 __logf(colsum[(t - 1) * K_DIM + tid]) -
                 __logf((float)N / (float)K_DIM);
        sv[tid] = vp;
        if (blockIdx.x == 0) vbuf[(t - 1) * K_DIM + tid] = vp;
    }
    __syncthreads();

    const int n = blockIdx.x * 512 + tid;
    float p[K_DIM];
    if (n < N) {
        const float4* Lr = (const float4*)(Lg + (size_t)n * K_DIM);
#pragma unroll
        for (int j = 0; j < 8; ++j) {
            const float4 lv = Lr[j];
            p[4 * j + 0] = lv.x - sv[4 * j + 0];
            p[4 * j + 1] = lv.y - sv[4 * j + 1];
            p[4 * j + 2] = lv.z - sv[4 * j + 2];
            p[4 * j + 3] = lv.w - sv[4 * j + 3];
        }
        float m0 = p[0];
#pragma unroll
        for (int j = 1; j < K_DIM; ++j) m0 = fmaxf(m0, p[j]);
        float sum = 0.f;
#pragma unroll
        for (int j = 0; j < K_DIM; ++j) {
            p[j] = __expf(p[j] - m0);
            sum += p[j];
        }
        const float inv = 1.f / sum;
#pragma unroll
        for (int j = 0; j < K_DIM; ++j) p[j] *= inv;
    } else {
#pragma unroll
        for (int j = 0; j < K_DIM; ++j) p[j] = 0.f;
    }

    // ---- fold-exchange column reduce across the 64-lane wave ----
#pragma unroll
    for (int s = 0; s < 5; ++s) {
        const int m = 1 << s;
        const int half = 32 >> (s + 1);   // 16,8,4,2,1
        const bool hi = (lane & m) != 0;
#pragma unroll
        for (int j = 0; j < 16; ++j) {
            if (j >= half) break;  // compile-time after unroll
            const float give = hi ? p[j] : p[j + half];
            const float keep = hi ? p[j + half] : p[j];
            const float recv = __shfl_xor(give, m);
            p[j] = keep + recv;
        }
    }
    const float tot = p[0] + __shfl_xor(p[0], 32);
    if (lane < 32) swsum[wave][bitrev5(lane)] = tot;
    __syncthreads();
    if (tid < K_DIM) {
        float s = 0.f;
#pragma unroll
        for (int w = 0; w < 8; ++w) s += swsum[w][tid];
        atomicAdd(&colsum[t * K_DIM + tid], s);
    }
}

// ---------------------------------------------------------------------------
// final pooling: s = exp(L - u - v20); out[b,k,c] += s[n,k]*x[n,c]
// batch sorted -> contiguous segments; register accumulators, flush on change.
// thread -> 4k x 4c outputs; 96-row LDS chunks (x + s staged).
// ---------------------------------------------------------------------------
#define PCHUNK 96
#define PCH_PER_BLOCK 4

__global__ __launch_bounds__(256) void pool_kernel(
    const float* __restrict__ x, const int* __restrict__ batch,
    const float* __restrict__ Lg, const float* __restrict__ vbuf,
    const float* __restrict__ colsum, float* __restrict__ out, int N) {
    __shared__ float sx[PCHUNK][C_DIM];   // 48 KB
    __shared__ float ss[PCHUNK][K_DIM];   // 12 KB
    __shared__ int sb[PCHUNK];
    __shared__ float sv19[K_DIM];
    __shared__ float sd[K_DIM];

    const int tid = threadIdx.x;
    if (tid < K_DIM) {
        sv19[tid] = vbuf[(N_ITERS - 1) * K_DIM + tid];
        // exp(v19 - v20) = (N/K) / colsum20
        sd[tid] = ((float)N / (float)K_DIM) / colsum[N_ITERS * K_DIM + tid];
    }
    __syncthreads();

    const int k0 = (tid >> 5) * 4;   // 0..28
    const int c0 = (tid & 31) * 4;   // 0..124
    float acc[4][4];
#pragma unroll
    for (int i = 0; i < 4; ++i)
#pragma unroll
        for (int j = 0; j < 4; ++j) acc[i][j] = 0.f;

    int cur_b = -1;
    const int base0 = blockIdx.x * (PCHUNK * PCH_PER_BLOCK);

    for (int cc = 0; cc < PCH_PER_BLOCK; ++cc) {
        const int base = base0 + cc * PCHUNK;
        if (base >= N) break;  // block-uniform
        const int rows = min(PCHUNK, N - base);
        __syncthreads();  // previous chunk fully consumed
        // stage x rows (contiguous, linear float4 copy)
        {
            const float4* src = (const float4*)(x + (size_t)base * C_DIM);
            for (int i = tid; i < rows * (C_DIM / 4); i += 256)
                ((float4*)&sx[0][0])[i] = src[i];
        }
        if (tid < rows) {
            sb[tid] = batch[base + tid];
            // compute s row
            const int n = base + tid;
            const float4* Lr = (const float4*)(Lg + (size_t)n * K_DIM);
            float p[K_DIM];
#pragma unroll
            for (int j = 0; j < 8; ++j) {
                const float4 lv = Lr[j];
                p[4 * j + 0] = lv.x - sv19[4 * j + 0];
                p[4 * j + 1] = lv.y - sv19[4 * j + 1];
                p[4 * j + 2] = lv.z - sv19[4 * j + 2];
                p[4 * j + 3] = lv.w - sv19[4 * j + 3];
            }
            float m0 = p[0];
#pragma unroll
            for (int j = 1; j < K_DIM; ++j) m0 = fmaxf(m0, p[j]);
            float sum = 0.f;
#pragma unroll
            for (int j = 0; j < K_DIM; ++j) {
                p[j] = __expf(p[j] - m0);
                sum += p[j];
            }
            const float inv = 1.f / sum;
#pragma unroll
            for (int j = 0; j < K_DIM; ++j) ss[tid][j] = p[j] * inv * sd[j];
        }
        __syncthreads();

        for (int r = 0; r < rows; ++r) {
            const int b = sb[r];  // uniform across block
            if (b != cur_b) {
                if (cur_b >= 0) {
                    float* ob = out + ((size_t)cur_b * K_DIM + k0) * C_DIM + c0;
#pragma unroll
                    for (int i = 0; i < 4; ++i)
#pragma unroll
                        for (int j = 0; j < 4; ++j) {
                            atomicAdd(&ob[i * C_DIM + j], acc[i][j]);
                            acc[i][j] = 0.f;
                        }
                }
                cur_b = b;
            }
            const float4 sv = *(const float4*)&ss[r][k0];
            const float4 xv = *(const float4*)&sx[r][c0];
            const float sA[4] = {sv.x, sv.y, sv.z, sv.w};
            const float xA[4] = {xv.x, xv.y, xv.z, xv.w};
#pragma unroll
            for (int i = 0; i < 4; ++i)
#pragma unroll
                for (int j = 0; j < 4; ++j)
                    acc[i][j] = fmaf(sA[i], xA[j], acc[i][j]);
        }
    }
    if (cur_b >= 0) {
        float* ob = out + ((size_t)cur_b * K_DIM + k0) * C_DIM + c0;
#pragma unroll
        for (int i = 0; i < 4; ++i)
#pragma unroll
            for (int j = 0; j < 4; ++j) atomicAdd(&ob[i * C_DIM + j], acc[i][j]);
    }
}

// ---------------------------------------------------------------------------
extern "C" void kernel_launch(void* const* d_in, const int* in_sizes, int n_in,
                              void* d_out, int out_size, void* d_ws, size_t ws_size,
                              hipStream_t stream) {
    const float* x = (const float*)d_in[0];
    const int* batch = (const int*)d_in[1];
    const float* W1 = (const float*)d_in[2];
    const float* b1 = (const float*)d_in[3];
    const float* W2 = (const float*)d_in[4];
    const float* b2 = (const float*)d_in[5];
    const float* scal = (const float*)d_in[6];
    float* out = (float*)d_out;

    const int N = in_sizes[1];  // 200000

    // ws layout: L [N*32] | vbuf [(ITERS+1)*32] | colsum [(ITERS+1)*32]
    float* Lg = (float*)d_ws;
    float* vbuf = Lg + (size_t)N * K_DIM;
    float* colsum = vbuf + (N_ITERS + 1) * K_DIM;

    init_kernel<<<64, 256, 0, stream>>>(out, vbuf, out_size,
                                        2 * (N_ITERS + 1) * K_DIM);

    const int ntiles = (N + 63) / 64;
    mlp_kernel<<<512, 512, 0, stream>>>(x, W1, b1, W2, b2, scal, Lg, N, ntiles);

    const int iblocks = (N + 511) / 512;
    for (int t = 1; t <= N_ITERS; ++t)
        sinkhorn_iter_kernel<<<iblocks, 512, 0, stream>>>(Lg, vbuf, colsum, t, N);

    const int pblocks = (N + PCHUNK * PCH_PER_BLOCK - 1) / (PCHUNK * PCH_PER_BLOCK);
    pool_kernel<<<pblocks, 256, 0, stream>>>(x, batch, Lg, vbuf, colsum, out, N);
}

// Round 5
// 561.065 us; speedup vs baseline: 1.9156x; 1.9156x over previous
//
#include <hip/hip_runtime.h>
#include <hip/hip_bf16.h>

// Problem constants (from setup_inputs): N=200000, C=128, K=32, B=16, 20 iters.
#define C_DIM 128
#define K_DIM 32
#define N_ITERS 20
#define SPAD 132            // padded sT row: rows r, r+1 differ by 132 words -> bank +4
#define NSHARD 8

// ---------------------------------------------------------------------------
// init: zero d_out accumulator, vbuf and colsum shards in ws
// ---------------------------------------------------------------------------
__global__ void init_kernel(float* __restrict__ out, float* __restrict__ vcs,
                            int n_out, int n_vcs) {
    int i = blockIdx.x * blockDim.x + threadIdx.x;
    int stride = gridDim.x * blockDim.x;
    for (int j = i; j < n_out; j += stride) out[j] = 0.f;
    for (int j = i; j < n_vcs; j += stride) vcs[j] = 0.f;
}

// ---------------------------------------------------------------------------
// fused MLP: logits = (relu(x@W1 + b1) @ W2 + b2) * scaling   -> L [N,32]
// 1024 threads (16 waves), 128-row tiles, W1/W2 staged ONCE per block
// (146 KB LDS -> 1 block/CU, 16 waves). Only 2 barriers per tile.
// wave w owns rows 8w..8w+7; lane l owns cols {2l,2l+1} in layer 1
// (x reads are same-address broadcasts; W1 float2 reads are a free 2-way).
// ---------------------------------------------------------------------------
__global__ __launch_bounds__(1024, 4) void mlp_kernel(
    const float* __restrict__ x, const float* __restrict__ W1,
    const float* __restrict__ b1, const float* __restrict__ W2,
    const float* __restrict__ b2, const float* __restrict__ scal,
    float* __restrict__ Lg, int N, int ntiles) {
    __shared__ float sW1[C_DIM * C_DIM];   // 64 KB, [k][c]
    __shared__ float sW2[C_DIM * K_DIM];   // 16 KB, [c][kk]
    __shared__ float sB1[C_DIM];
    __shared__ float sB2[K_DIM];
    __shared__ float sT[128][SPAD];        // 66 KB padded: x tile then h tile

    const int tid = threadIdx.x;
    for (int i = tid; i < C_DIM * C_DIM / 4; i += 1024)
        ((float4*)sW1)[i] = ((const float4*)W1)[i];
    for (int i = tid; i < C_DIM * K_DIM / 4; i += 1024)
        ((float4*)sW2)[i] = ((const float4*)W2)[i];
    if (tid < C_DIM / 4) ((float4*)sB1)[tid] = ((const float4*)b1)[tid];
    if (tid < K_DIM / 4) ((float4*)sB2)[tid] = ((const float4*)b2)[tid];
    const float sc = *scal;

    const int wave = tid >> 6;   // 0..15
    const int lane = tid & 63;
    const int r0 = wave * 8;

    for (int tile = blockIdx.x; tile < ntiles; tile += gridDim.x) {
        const int row0 = tile * 128;
        const int rows = min(128, N - row0);
        __syncthreads();  // previous tile fully consumed before overwrite
        // ---- stage x tile into padded sT ----
        {
            const float4* src = (const float4*)(x + (size_t)row0 * C_DIM);
            for (int i = tid; i < rows * 32; i += 1024) {
                const int r = i >> 5, cq = i & 31;
                ((float4*)&sT[r][0])[cq] = src[i];
            }
        }
        __syncthreads();

        // ---- layer 1: h = relu(x@W1 + b1), 8 rows x 2 cols per lane ----
        float acc[8][2];
#pragma unroll
        for (int r = 0; r < 8; ++r) {
            acc[r][0] = sB1[2 * lane];
            acc[r][1] = sB1[2 * lane + 1];
        }
#pragma unroll 2
        for (int kc = 0; kc < 32; ++kc) {
            const int k = kc * 4;
            const float2 w0 = *(const float2*)&sW1[(k + 0) * C_DIM + 2 * lane];
            const float2 w1 = *(const float2*)&sW1[(k + 1) * C_DIM + 2 * lane];
            const float2 w2 = *(const float2*)&sW1[(k + 2) * C_DIM + 2 * lane];
            const float2 w3 = *(const float2*)&sW1[(k + 3) * C_DIM + 2 * lane];
#pragma unroll
            for (int r = 0; r < 8; ++r) {
                const float4 xv = *(const float4*)&sT[r0 + r][k];  // broadcast
                acc[r][0] = fmaf(xv.x, w0.x, acc[r][0]);
                acc[r][1] = fmaf(xv.x, w0.y, acc[r][1]);
                acc[r][0] = fmaf(xv.y, w1.x, acc[r][0]);
                acc[r][1] = fmaf(xv.y, w1.y, acc[r][1]);
                acc[r][0] = fmaf(xv.z, w2.x, acc[r][0]);
                acc[r][1] = fmaf(xv.z, w2.y, acc[r][1]);
                acc[r][0] = fmaf(xv.w, w3.x, acc[r][0]);
                acc[r][1] = fmaf(xv.w, w3.y, acc[r][1]);
            }
        }
        // write h back into own rows (program-order LDS dependence is safe)
#pragma unroll
        for (int r = 0; r < 8; ++r) {
            float2 hv;
            hv.x = fmaxf(acc[r][0], 0.f);
            hv.y = fmaxf(acc[r][1], 0.f);
            *(float2*)&sT[r0 + r][2 * lane] = hv;
        }

        // ---- layer 2: logits = (h@W2 + b2)*sc ; 1 row x 4 kk per lane ----
        // (reads only this wave's rows of sT -> no block sync needed)
        const int r2 = lane & 7;
        const int kk0 = (lane >> 3) * 4;
        float a2[4];
        a2[0] = sB2[kk0];
        a2[1] = sB2[kk0 + 1];
        a2[2] = sB2[kk0 + 2];
        a2[3] = sB2[kk0 + 3];
#pragma unroll 4
        for (int c = 0; c < C_DIM; c += 4) {
            const float4 hv = *(const float4*)&sT[r0 + r2][c];
            const float4 q0 = *(const float4*)&sW2[(c + 0) * K_DIM + kk0];
            const float4 q1 = *(const float4*)&sW2[(c + 1) * K_DIM + kk0];
            const float4 q2 = *(const float4*)&sW2[(c + 2) * K_DIM + kk0];
            const float4 q3 = *(const float4*)&sW2[(c + 3) * K_DIM + kk0];
            a2[0] = fmaf(hv.x, q0.x, a2[0]); a2[1] = fmaf(hv.x, q0.y, a2[1]);
            a2[2] = fmaf(hv.x, q0.z, a2[2]); a2[3] = fmaf(hv.x, q0.w, a2[3]);
            a2[0] = fmaf(hv.y, q1.x, a2[0]); a2[1] = fmaf(hv.y, q1.y, a2[1]);
            a2[2] = fmaf(hv.y, q1.z, a2[2]); a2[3] = fmaf(hv.y, q1.w, a2[3]);
            a2[0] = fmaf(hv.z, q2.x, a2[0]); a2[1] = fmaf(hv.z, q2.y, a2[1]);
            a2[2] = fmaf(hv.z, q2.z, a2[2]); a2[3] = fmaf(hv.z, q2.w, a2[3]);
            a2[0] = fmaf(hv.w, q3.x, a2[0]); a2[1] = fmaf(hv.w, q3.y, a2[1]);
            a2[2] = fmaf(hv.w, q3.z, a2[2]); a2[3] = fmaf(hv.w, q3.w, a2[3]);
        }
        const int g = row0 + r0 + r2;
        if (g < N) {
            float4 o = make_float4(a2[0] * sc, a2[1] * sc, a2[2] * sc, a2[3] * sc);
            *(float4*)&Lg[(size_t)g * K_DIM + kk0] = o;
        }
    }
}

// ---------------------------------------------------------------------------
// one Sinkhorn iteration t (1-based), separate launch per t (kernel-boundary
// coherence is the grid sync; validated structure from rounds 1-2):
//   v_{t-1} = vbuf[t-2] + log(sum_sh shards[t-1]) - log(N/K)  (per block)
//   per row: u = LSE_k(L - v_{t-1}); accumulate shards[t, blk&7] column sums
// Column reduce: compile-time fold-exchange (16+8+4+2+1 shfl) + final xor32.
// Lane l ends holding the 64-lane sum of column bitrev5(l&31).
// ---------------------------------------------------------------------------
__device__ __forceinline__ int bitrev5(int l) {
    return ((l & 1) << 4) | ((l & 2) << 2) | (l & 4) | ((l & 8) >> 2) |
           ((l & 16) >> 4);
}

#define FOLD_STAGE(M, HALF)                                   \
    {                                                         \
        const bool hi = (lane & (M)) != 0;                    \
        _Pragma("unroll")                                     \
        for (int j = 0; j < (HALF); ++j) {                    \
            const float give = hi ? p[j] : p[j + (HALF)];     \
            const float keep = hi ? p[j + (HALF)] : p[j];     \
            p[j] = keep + __shfl_xor(give, (M));              \
        }                                                     \
    }

__global__ __launch_bounds__(1024) void sinkhorn_iter_kernel(
    const float* __restrict__ Lg, float* __restrict__ vbuf,
    float* __restrict__ shards, int t, int N) {
    __shared__ float sv[K_DIM];
    __shared__ float swsum[16][K_DIM];
    const int tid = threadIdx.x;
    const int wave = tid >> 6;
    const int lane = tid & 63;

    if (tid < K_DIM) {
        float vp = 0.f;
        if (t > 1) {
            float cs = 0.f;
#pragma unroll
            for (int sh = 0; sh < NSHARD; ++sh)
                cs += shards[((size_t)(t - 1) * NSHARD + sh) * K_DIM + tid];
            vp = vbuf[(t - 2) * K_DIM + tid] + __logf(cs) -
                 __logf((float)N / (float)K_DIM);
        }
        sv[tid] = vp;
        if (blockIdx.x == 0) vbuf[(t - 1) * K_DIM + tid] = vp;
    }
    __syncthreads();

    const size_t n = (size_t)blockIdx.x * 1024 + tid;
    float p[K_DIM];
    if (n < (size_t)N) {
        const float4* Lr = (const float4*)(Lg + n * K_DIM);
#pragma unroll
        for (int j = 0; j < 8; ++j) {
            const float4 lv = Lr[j];
            p[4 * j + 0] = lv.x - sv[4 * j + 0];
            p[4 * j + 1] = lv.y - sv[4 * j + 1];
            p[4 * j + 2] = lv.z - sv[4 * j + 2];
            p[4 * j + 3] = lv.w - sv[4 * j + 3];
        }
        float m0 = p[0];
#pragma unroll
        for (int j = 1; j < K_DIM; ++j) m0 = fmaxf(m0, p[j]);
        float sum = 0.f;
#pragma unroll
        for (int j = 0; j < K_DIM; ++j) {
            p[j] = __expf(p[j] - m0);
            sum += p[j];
        }
        const float inv = 1.f / sum;
#pragma unroll
        for (int j = 0; j < K_DIM; ++j) p[j] *= inv;
    } else {
#pragma unroll
        for (int j = 0; j < K_DIM; ++j) p[j] = 0.f;
    }

    // ---- fold-exchange column reduce (all indices compile-time) ----
    FOLD_STAGE(1, 16)
    FOLD_STAGE(2, 8)
    FOLD_STAGE(4, 4)
    FOLD_STAGE(8, 2)
    FOLD_STAGE(16, 1)
    const float tot = p[0] + __shfl_xor(p[0], 32);
    if (lane < K_DIM) swsum[wave][bitrev5(lane)] = tot;
    __syncthreads();
    if (tid < K_DIM) {
        float s_ = 0.f;
#pragma unroll
        for (int w = 0; w < 16; ++w) s_ += swsum[w][tid];
        atomicAdd(&shards[((size_t)t * NSHARD + (blockIdx.x & (NSHARD - 1))) *
                              K_DIM + tid], s_);
    }
}

// ---------------------------------------------------------------------------
// final pooling: s = exp(L - v19 - u) * sd; out[b,k,c] += s[n,k]*x[n,c]
// (round-2 validated kernel; sd now sourced from summed shards)
// batch sorted -> contiguous segments; register accumulators, flush on change.
// thread -> 4k x 4c outputs; 96-row LDS chunks (x + s staged).
// ---------------------------------------------------------------------------
#define PCHUNK 96
#define PCH_PER_BLOCK 4

__global__ __launch_bounds__(256) void pool_kernel(
    const float* __restrict__ x, const int* __restrict__ batch,
    const float* __restrict__ Lg, const float* __restrict__ vbuf,
    const float* __restrict__ shards, float* __restrict__ out, int N) {
    __shared__ float sx[PCHUNK][C_DIM];   // 48 KB
    __shared__ float ss[PCHUNK][K_DIM];   // 12 KB
    __shared__ int sb[PCHUNK];
    __shared__ float sv19[K_DIM];
    __shared__ float sd[K_DIM];

    const int tid = threadIdx.x;
    if (tid < K_DIM) {
        sv19[tid] = vbuf[(N_ITERS - 1) * K_DIM + tid];
        float cs = 0.f;
#pragma unroll
        for (int sh = 0; sh < NSHARD; ++sh)
            cs += shards[((size_t)N_ITERS * NSHARD + sh) * K_DIM + tid];
        // exp(v19 - v20) = (N/K) / colsum20
        sd[tid] = ((float)N / (float)K_DIM) / cs;
    }
    __syncthreads();

    const int k0 = (tid >> 5) * 4;   // 0..28
    const int c0 = (tid & 31) * 4;   // 0..124
    float acc[4][4];
#pragma unroll
    for (int i = 0; i < 4; ++i)
#pragma unroll
        for (int j = 0; j < 4; ++j) acc[i][j] = 0.f;

    int cur_b = -1;
    const int base0 = blockIdx.x * (PCHUNK * PCH_PER_BLOCK);

    for (int cc = 0; cc < PCH_PER_BLOCK; ++cc) {
        const int base = base0 + cc * PCHUNK;
        if (base >= N) break;  // block-uniform
        const int rows = min(PCHUNK, N - base);
        __syncthreads();  // previous chunk fully consumed
        // stage x rows (contiguous, linear float4 copy)
        {
            const float4* src = (const float4*)(x + (size_t)base * C_DIM);
            for (int i = tid; i < rows * (C_DIM / 4); i += 256)
                ((float4*)&sx[0][0])[i] = src[i];
        }
        if (tid < rows) {
            sb[tid] = batch[base + tid];
            // compute s row
            const int n = base + tid;
            const float4* Lr = (const float4*)(Lg + (size_t)n * K_DIM);
            float p[K_DIM];
#pragma unroll
            for (int j = 0; j < 8; ++j) {
                const float4 lv = Lr[j];
                p[4 * j + 0] = lv.x - sv19[4 * j + 0];
                p[4 * j + 1] = lv.y - sv19[4 * j + 1];
                p[4 * j + 2] = lv.z - sv19[4 * j + 2];
                p[4 * j + 3] = lv.w - sv19[4 * j + 3];
            }
            float m0 = p[0];
#pragma unroll
            for (int j = 1; j < K_DIM; ++j) m0 = fmaxf(m0, p[j]);
            float sum = 0.f;
#pragma unroll
            for (int j = 0; j < K_DIM; ++j) {
                p[j] = __expf(p[j] - m0);
                sum += p[j];
            }
            const float inv = 1.f / sum;
#pragma unroll
            for (int j = 0; j < K_DIM; ++j) ss[tid][j] = p[j] * inv * sd[j];
        }
        __syncthreads();

        for (int r = 0; r < rows; ++r) {
            const int b = sb[r];
            if (b != cur_b) {
                if (cur_b >= 0) {
                    float* ob = out + ((size_t)cur_b * K_DIM + k0) * C_DIM + c0;
#pragma unroll
                    for (int i = 0; i < 4; ++i)
#pragma unroll
                        for (int j = 0; j < 4; ++j) {
                            atomicAdd(&ob[i * C_DIM + j], acc[i][j]);
                            acc[i][j] = 0.f;
                        }
                }
                cur_b = b;
            }
            const float4 sv = *(const float4*)&ss[r][k0];
            const float4 xv = *(const float4*)&sx[r][c0];
            const float sA[4] = {sv.x, sv.y, sv.z, sv.w};
            const float xA[4] = {xv.x, xv.y, xv.z, xv.w};
#pragma unroll
            for (int i = 0; i < 4; ++i)
#pragma unroll
                for (int j = 0; j < 4; ++j)
                    acc[i][j] = fmaf(sA[i], xA[j], acc[i][j]);
        }
    }
    if (cur_b >= 0) {
        float* ob = out + ((size_t)cur_b * K_DIM + k0) * C_DIM + c0;
#pragma unroll
        for (int i = 0; i < 4; ++i)
#pragma unroll
            for (int j = 0; j < 4; ++j) atomicAdd(&ob[i * C_DIM + j], acc[i][j]);
    }
}

// ---------------------------------------------------------------------------
extern "C" void kernel_launch(void* const* d_in, const int* in_sizes, int n_in,
                              void* d_out, int out_size, void* d_ws, size_t ws_size,
                              hipStream_t stream) {
    const float* x = (const float*)d_in[0];
    const int* batch = (const int*)d_in[1];
    const float* W1 = (const float*)d_in[2];
    const float* b1 = (const float*)d_in[3];
    const float* W2 = (const float*)d_in[4];
    const float* b2 = (const float*)d_in[5];
    const float* scal = (const float*)d_in[6];
    float* out = (float*)d_out;

    const int N = in_sizes[1];  // 200000

    // ws layout: L [N*32] | vbuf [(ITERS+1)*32] | shards [(ITERS+1)*8*32]
    float* Lg = (float*)d_ws;
    float* vbuf = Lg + (size_t)N * K_DIM;
    float* shards = vbuf + (N_ITERS + 1) * K_DIM;
    const int n_vcs = (N_ITERS + 1) * K_DIM + (N_ITERS + 1) * NSHARD * K_DIM;

    init_kernel<<<64, 256, 0, stream>>>(out, vbuf, out_size, n_vcs);

    const int ntiles = (N + 127) / 128;
    mlp_kernel<<<256, 1024, 0, stream>>>(x, W1, b1, W2, b2, scal, Lg, N, ntiles);

    const int iblocks = (N + 1023) / 1024;  // 196
    for (int t = 1; t <= N_ITERS; ++t)
        sinkhorn_iter_kernel<<<iblocks, 1024, 0, stream>>>(Lg, vbuf, shards, t, N);

    const int pblocks = (N + PCHUNK * PCH_PER_BLOCK - 1) / (PCHUNK * PCH_PER_BLOCK);
    pool_kernel<<<pblocks, 256, 0, stream>>>(x, batch, Lg, vbuf, shards, out, N);
}